// Round 7
// baseline (295.704 us; speedup 1.0000x reference)
//
#include <hip/hip_runtime.h>
#include <stdint.h>

#define B_  4
#define S_  2048
#define DM_ 1024
#define NH_ 16
#define HD_ 64
#define QSCALE 0.1803368801f   // 0.125 * log2(e): exp2-domain softmax scale

typedef unsigned short ushort_t;
typedef __bf16 bf16x8 __attribute__((ext_vector_type(8)));
typedef float  floatx4 __attribute__((ext_vector_type(4)));
typedef float  floatx16 __attribute__((ext_vector_type(16)));

__device__ __forceinline__ float bf2f(ushort_t u) {
    union { unsigned int i; float f; } v; v.i = ((unsigned int)u) << 16; return v.f;
}
__device__ __forceinline__ ushort_t f2bf(float f) {
    union { float f; unsigned int i; } v; v.f = f;
    unsigned int x = v.i;
    return (ushort_t)((x + 0x7fffu + ((x >> 16) & 1u)) >> 16);
}
__device__ __forceinline__ unsigned int pack_bf16_trunc(float lo, float hi) {
    union { float f; unsigned int u; } a, b;
    a.f = lo; b.f = hi;
    return __builtin_amdgcn_perm(b.u, a.u, 0x07060302u);
}

// ---------------------------------------------------------------------------
// fused f32 -> bf16 conversion: x (8192 blocks) + 4 weights (1024 each)
// ---------------------------------------------------------------------------
__global__ __launch_bounds__(256) void cvt_all_kernel(
    const float* __restrict__ x,  const float* __restrict__ wq,
    const float* __restrict__ wk, const float* __restrict__ wv,
    const float* __restrict__ wo,
    ushort_t* __restrict__ xb,  ushort_t* __restrict__ wqb,
    ushort_t* __restrict__ wkb, ushort_t* __restrict__ wvb,
    ushort_t* __restrict__ wob)
{
    const int blk = blockIdx.x;
    const float* src; ushort_t* dst; int off;
    if (blk < 8192)       { src = x;  dst = xb;  off = blk; }
    else if (blk < 9216)  { src = wq; dst = wqb; off = blk - 8192; }
    else if (blk < 10240) { src = wk; dst = wkb; off = blk - 9216; }
    else if (blk < 11264) { src = wv; dst = wvb; off = blk - 10240; }
    else                  { src = wo; dst = wob; off = blk - 11264; }
    const int i = off * 256 + threadIdx.x;
    float4 v = ((const float4*)src)[i];
    ushort4 o; o.x = f2bf(v.x); o.y = f2bf(v.y); o.z = f2bf(v.z); o.w = f2bf(v.w);
    ((ushort4*)dst)[i] = o;
}

// ---------------------------------------------------------------------------
// GEMM: C = A @ B^T, BK=32, 32x32x16 MFMA, 2x2 wave grid, 2x2 tiles/wave.
// LDS chunk swizzle: row r's 16B chunk c_p holds logical chunk (c_p-(r>>1))&3
// -> frag reads hit all 8 bank-quads per 8-lane group (conflict-free),
//    staging keeps 64B-per-row coalescing (chunks permuted within the row).
// Epilogues (z selects weight/output):
//   mode 0, z=0: Q = rope(x@wq^T)*QSCALE -> (B,H,S,64), b32 pair stores
//   mode 0, z=1: K = rope(x@wk^T)        -> (B,H,S,64), b32 pair stores
//   mode 0, z=2: V^T                     -> (B,H,64,S), b64 packed along s
//   mode 1     : f32 row-major, float2 pair stores
// ---------------------------------------------------------------------------
__global__ __launch_bounds__(256, 4) void gemm_bt_kernel(
    const ushort_t* __restrict__ A,
    const ushort_t* __restrict__ B0, const ushort_t* __restrict__ B1,
    const ushort_t* __restrict__ B2,
    void* __restrict__ C0, void* __restrict__ C1, void* __restrict__ C2,
    const float* __restrict__ cf, const float* __restrict__ sf,
    int M, int N, int K, int mode)
{
    __shared__ ushort_t As[128 * 32];
    __shared__ ushort_t Bs[128 * 32];
    const int z = blockIdx.z;
    const ushort_t* Bw = z == 0 ? B0 : z == 1 ? B1 : B2;
    void* Cv           = z == 0 ? C0 : z == 1 ? C1 : C2;

    const int tid  = threadIdx.x;
    const int mbase = blockIdx.x * 128;
    const int nbase = blockIdx.y * 128;
    const int wave = tid >> 6, lane = tid & 63;
    const int l31 = lane & 31, h = lane >> 5;
    const int wm = (wave & 1) * 64, wn = (wave >> 1) * 64;

    floatx16 acc[2][2] = {};

    const int e0 = tid * 8;
    for (int kt = 0; kt < K; kt += 32) {
        __syncthreads();
#pragma unroll
        for (int r = 0; r < 2; ++r) {
            const int e   = e0 + r * 2048;
            const int row = e >> 5;
            const int cp  = (e >> 3) & 3;
            const int cl  = (cp - (row >> 1)) & 3;   // logical chunk stored here
            const ushort_t* ga = A  + (size_t)(mbase + row) * K + kt + cl * 8;
            const ushort_t* gb = Bw + (size_t)(nbase + row) * K + kt + cl * 8;
            __builtin_amdgcn_global_load_lds(
                (const __attribute__((address_space(1))) unsigned int*)ga,
                (__attribute__((address_space(3))) unsigned int*)(As + e), 16, 0, 0);
            __builtin_amdgcn_global_load_lds(
                (const __attribute__((address_space(1))) unsigned int*)gb,
                (__attribute__((address_space(3))) unsigned int*)(Bs + e), 16, 0, 0);
        }
        __builtin_amdgcn_s_waitcnt(0);
        __syncthreads();

#pragma unroll
        for (int kk = 0; kk < 2; ++kk) {
            const int cswz = (kk * 2 + h + (l31 >> 1)) & 3;   // physical chunk
            bf16x8 af[2], bfr[2];
#pragma unroll
            for (int t = 0; t < 2; ++t) {
                af[t]  = *(const bf16x8*)(As + (wm + t * 32 + l31) * 32 + cswz * 8);
                bfr[t] = *(const bf16x8*)(Bs + (wn + t * 32 + l31) * 32 + cswz * 8);
            }
#pragma unroll
            for (int mt = 0; mt < 2; ++mt)
#pragma unroll
                for (int nt = 0; nt < 2; ++nt)
                    acc[mt][nt] = __builtin_amdgcn_mfma_f32_32x32x16_bf16(
                        af[mt], bfr[nt], acc[mt][nt], 0, 0, 0);
        }
    }

    // ---- epilogues. 32x32 C layout: col=n=l31, row=m=(reg&3)+8*(reg>>2)+4h
    const int p = l31 & 1;
    if (mode == 0 && z < 2) {
        // rope(Q/K): pair (d even, d odd) lives in adjacent lanes
        ushort_t* Qo = (ushort_t*)Cv;
        const float qs = (z == 0) ? QSCALE : 1.0f;
#pragma unroll
        for (int mt = 0; mt < 2; ++mt)
#pragma unroll
        for (int nt = 0; nt < 2; ++nt) {
            const int col = nbase + wn + nt * 32 + l31;
            const int hh = col >> 6, j = (col & 63) >> 1, de = col & 62;
            float other[16];
#pragma unroll
            for (int i = 0; i < 16; ++i)
                other[i] = __shfl_xor(acc[mt][nt][i], 1, 64);
#pragma unroll
            for (int u = 0; u < 8; ++u) {
                const int i = p * 8 + u;   // even lanes: regs 0-7; odd: 8-15
                const int m = mbase + wm + mt * 32 + (i & 3) + 8 * (i >> 2) + 4 * h;
                const int bb = m >> 11, ss = m & 2047;   // ss = seq position
                const float my = acc[mt][nt][i], ot = other[i];
                const float e = p ? ot : my;
                const float o = p ? my : ot;
                const float c = cf[ss * 32 + j], sn = sf[ss * 32 + j];
                const float oe = (e * c - o * sn) * qs;
                const float oo = (e * sn + o * c) * qs;
                unsigned pk = (unsigned)f2bf(oe) | ((unsigned)f2bf(oo) << 16);
                *(unsigned*)&Qo[(((size_t)(bb * NH_ + hh)) * S_ + ss) * HD_ + de] = pk;
            }
        }
    } else if (mode == 0) {
        // V^T: pack 4 consecutive s at fixed d
        ushort_t* Vo = (ushort_t*)Cv;
#pragma unroll
        for (int mt = 0; mt < 2; ++mt)
#pragma unroll
        for (int nt = 0; nt < 2; ++nt) {
            const int col = nbase + wn + nt * 32 + l31;
            const int hh = col >> 6, d = col & 63;
#pragma unroll
            for (int c = 0; c < 4; ++c) {
                const int s0 = mbase + wm + mt * 32 + 8 * c + 4 * h;
                const int bb = s0 >> 11, ss = s0 & 2047;
                uint2 pk;
                pk.x = (unsigned)f2bf(acc[mt][nt][c * 4 + 0]) |
                       ((unsigned)f2bf(acc[mt][nt][c * 4 + 1]) << 16);
                pk.y = (unsigned)f2bf(acc[mt][nt][c * 4 + 2]) |
                       ((unsigned)f2bf(acc[mt][nt][c * 4 + 3]) << 16);
                *(uint2*)&Vo[((size_t)((bb * NH_ + hh) * HD_ + d)) * S_ + ss] = pk;
            }
        }
    } else {
        // f32 row-major, pair-packed float2 stores
        float* Co = (float*)Cv;
#pragma unroll
        for (int mt = 0; mt < 2; ++mt)
#pragma unroll
        for (int nt = 0; nt < 2; ++nt) {
            const int col = nbase + wn + nt * 32 + l31;
            float other[16];
#pragma unroll
            for (int i = 0; i < 16; ++i)
                other[i] = __shfl_xor(acc[mt][nt][i], 1, 64);
#pragma unroll
            for (int u = 0; u < 8; ++u) {
                const int i = p * 8 + u;
                const int m = mbase + wm + mt * 32 + (i & 3) + 8 * (i >> 2) + 4 * h;
                float2 v;
                v.x = p ? other[i] : acc[mt][nt][i];
                v.y = p ? acc[mt][nt][i] : other[i];
                *(float2*)&Co[(size_t)m * N + (col & ~1)] = v;
            }
        }
    }
}

// ---------------------------------------------------------------------------
// Causal flash attention, S^T/O^T with 32x32x16 MFMA, exp2-domain softmax.
// Q,K in (B,H,S,64) (Q pre-scaled+roped); V in (B,H,64,S) pre-transposed.
// Block = 4 waves x 32 q-rows; pairs {p,15-p} for uniform 34 tiles.
// ---------------------------------------------------------------------------
__global__ __launch_bounds__(256, 2) void attn_kernel(
    const ushort_t* __restrict__ Qg, const ushort_t* __restrict__ Kg,
    const ushort_t* __restrict__ Vg, ushort_t* __restrict__ Og)
{
    __shared__ ushort_t Ks[64 * 72];       // [key][dim], pad 72
    __shared__ ushort_t Vt[64 * 72];       // [dim][key ^ chunk-swizzle], pad 72
    __shared__ ushort_t Pt[4][32 * 64];    // per-wave P^T [q][key ^ swizzle]

    const int pair = blockIdx.x;           // 0..7
    const int bh   = blockIdx.y;
    const int tid  = threadIdx.x;
    const int wave = tid >> 6, lane = tid & 63;
    const int l31 = lane & 31, h = lane >> 5;

    const size_t bh_off = (size_t)bh * S_ * HD_;
    const int trow = tid >> 3;             // 0..31
    const int tcol = (tid & 7) * 8;        // 0..56
    const int pswz = (l31 & 7) << 3;
    const int b_out = bh >> 4, h_out = bh & 15;

#pragma unroll 1
    for (int seg = 0; seg < 2; ++seg) {
        const int qtile = seg ? (15 - pair) : pair;
        const int qbase = qtile * 128;
        const int nkt   = 2 * qtile + 2;
        const int qrow  = qbase + wave * 32 + l31;

        bf16x8 qf[4];
#pragma unroll
        for (int ks = 0; ks < 4; ++ks)
            qf[ks] = *(const bf16x8*)(Qg + bh_off + (size_t)qrow * HD_ + ks * 16 + h * 8);

        float m_run = -1e30f, l_run = 0.f;
        floatx16 o_acc[2] = {};

        for (int kt = 0; kt < nkt; ++kt) {
            const int kbase = kt * 64;
            __syncthreads();
            // ---- stage K [key][dim] and V^T [dim][key^swz] — all b128 ----
#pragma unroll
            for (int r = 0; r < 2; ++r) {
                const int row = trow + r * 32;
                *(bf16x8*)(Ks + row * 72 + tcol) =
                    *(const bf16x8*)(Kg + bh_off + (size_t)(kbase + row) * HD_ + tcol);
                const int c = tid + r * 256;
                const int d = c >> 3, k0 = (c & 7) * 8;
                bf16x8 vv = *(const bf16x8*)(Vg + bh_off + (size_t)d * S_ + kbase + k0);
                *(bf16x8*)(Vt + d * 72 + (k0 ^ (((d >> 3) & 7) << 3))) = vv;
            }
            __syncthreads();

            if (kbase > qbase + wave * 32 + 31) continue;   // fully masked

            // ---- S^T = K·Q^T ----
            floatx16 st[2] = {};
#pragma unroll
            for (int nt = 0; nt < 2; ++nt) {
                const ushort_t* kr = Ks + (nt * 32 + l31) * 72 + h * 8;
#pragma unroll
                for (int ks = 0; ks < 4; ++ks) {
                    bf16x8 kf = *(const bf16x8*)(kr + ks * 16);
                    st[nt] = __builtin_amdgcn_mfma_f32_32x32x16_bf16(kf, qf[ks], st[nt], 0, 0, 0);
                }
            }
            // ---- causal mask (diagonal tiles only) ----
            if (kbase + 63 > qbase + wave * 32) {
#pragma unroll
                for (int nt = 0; nt < 2; ++nt) {
                    const int key0 = kbase + nt * 32 + 4 * h;
#pragma unroll
                    for (int c = 0; c < 4; ++c)
#pragma unroll
                        for (int r = 0; r < 4; ++r)
                            if (key0 + 8 * c + r > qrow) st[nt][c * 4 + r] = -1e9f;
                }
            }
            // ---- online softmax, exp2 domain ----
            float mx = st[0][0];
#pragma unroll
            for (int nt = 0; nt < 2; ++nt)
#pragma unroll
                for (int i = 0; i < 16; ++i) mx = fmaxf(mx, st[nt][i]);
            mx = fmaxf(mx, __shfl_xor(mx, 32, 64));
            const float mnew = fmaxf(m_run, mx);
            const float alpha = __builtin_amdgcn_exp2f(m_run - mnew);
            m_run = mnew;
            float sum = 0.f;
#pragma unroll
            for (int nt = 0; nt < 2; ++nt)
#pragma unroll
                for (int i = 0; i < 16; ++i) {
                    const float pv = __builtin_amdgcn_exp2f(st[nt][i] - mnew);
                    st[nt][i] = pv; sum += pv;
                }
            sum += __shfl_xor(sum, 32, 64);
            l_run = l_run * alpha + sum;
#pragma unroll
            for (int dt = 0; dt < 2; ++dt)
#pragma unroll
                for (int i = 0; i < 16; ++i) o_acc[dt][i] *= alpha;

            // ---- P^T -> wave-private LDS [q][key^swz] (b64 stores) ----
            ushort_t* pr = &Pt[wave][l31 * 64];
#pragma unroll
            for (int nt = 0; nt < 2; ++nt)
#pragma unroll
                for (int c = 0; c < 4; ++c) {
                    uint2 pk;
                    pk.x = pack_bf16_trunc(st[nt][c * 4 + 0], st[nt][c * 4 + 1]);
                    pk.y = pack_bf16_trunc(st[nt][c * 4 + 2], st[nt][c * 4 + 3]);
                    *(uint2*)(pr + (((nt * 32 + 8 * c) ^ pswz) + 4 * h)) = pk;
                }
            __builtin_amdgcn_fence(__ATOMIC_ACQ_REL, "wavefront");
            __builtin_amdgcn_wave_barrier();

            bf16x8 pf[4];
#pragma unroll
            for (int ks = 0; ks < 4; ++ks)
                pf[ks] = *(const bf16x8*)(&Pt[wave][l31 * 64 + ((ks * 16 + h * 8) ^ pswz)]);

            // ---- O^T += V^T·P^T ----
#pragma unroll
            for (int dt = 0; dt < 2; ++dt) {
                const int d = dt * 32 + l31;
                const int sw = ((d >> 3) & 7) << 3;
                const ushort_t* vr = Vt + d * 72;
#pragma unroll
                for (int ks = 0; ks < 4; ++ks) {
                    bf16x8 vf = *(const bf16x8*)(vr + ((ks * 16 + h * 8) ^ sw));
                    o_acc[dt] = __builtin_amdgcn_mfma_f32_32x32x16_bf16(vf, pf[ks], o_acc[dt], 0, 0, 0);
                }
            }
        }

        // ---- epilogue: normalize, write bf16 (B,S,H*64) ----
        const float inv = 1.0f / l_run;
        ushort_t* orow = Og + ((size_t)(b_out * S_ + qrow)) * DM_ + h_out * HD_;
#pragma unroll
        for (int dt = 0; dt < 2; ++dt)
#pragma unroll
            for (int c = 0; c < 4; ++c) {
                uint2 pk;
                pk.x = (unsigned)f2bf(o_acc[dt][c * 4 + 0] * inv) |
                       ((unsigned)f2bf(o_acc[dt][c * 4 + 1] * inv) << 16);
                pk.y = (unsigned)f2bf(o_acc[dt][c * 4 + 2] * inv) |
                       ((unsigned)f2bf(o_acc[dt][c * 4 + 3] * inv) << 16);
                *(uint2*)(orow + dt * 32 + 8 * c + 4 * h) = pk;
            }
    }
}

// ---------------------------------------------------------------------------
extern "C" void kernel_launch(void* const* d_in, const int* in_sizes, int n_in,
                              void* d_out, int out_size, void* d_ws, size_t ws_size,
                              hipStream_t stream)
{
    const float* x  = (const float*)d_in[0];
    const float* cf = (const float*)d_in[1];
    const float* sf = (const float*)d_in[2];
    // d_in[3] = causal_mask: computed analytically, never read
    const float* wq = (const float*)d_in[4];
    const float* wk = (const float*)d_in[5];
    const float* wv = (const float*)d_in[6];
    const float* wo = (const float*)d_in[7];
    float* out = (float*)d_out;

    const size_t NELEM = (size_t)B_ * S_ * DM_;   // 8388608
    const size_t WELEM = (size_t)DM_ * DM_;       // 1048576
    ushort_t* xb  = (ushort_t*)d_ws;
    ushort_t* qb  = xb + NELEM;
    ushort_t* kb  = qb + NELEM;
    ushort_t* vb  = kb + NELEM;                   // V^T (B,H,64,S)
    ushort_t* ao  = vb + NELEM;
    ushort_t* wqb = ao + NELEM;
    ushort_t* wkb = wqb + WELEM;
    ushort_t* wvb = wkb + WELEM;
    ushort_t* wob = wvb + WELEM;

    cvt_all_kernel<<<dim3(8192 + 4 * 1024), 256, 0, stream>>>(
        x, wq, wk, wv, wo, xb, wqb, wkb, wvb, wob);

    const int M = B_ * S_;
    // fused QKV GEMM with in-epilogue RoPE (Q,K) and V^T store
    gemm_bt_kernel<<<dim3(M / 128, DM_ / 128, 3), 256, 0, stream>>>(
        xb, wqb, wkb, wvb, qb, kb, vb, cf, sf, M, DM_, DM_, 0);
    attn_kernel<<<dim3(8, B_ * NH_), 256, 0, stream>>>(qb, kb, vb, ao);
    gemm_bt_kernel<<<dim3(M / 128, DM_ / 128, 1), 256, 0, stream>>>(
        ao, wob, wob, wob, out, out, out, cf, sf, M, DM_, DM_, 1);
}

// Round 8
// 292.212 us; speedup vs baseline: 1.0120x; 1.0120x over previous
//
#include <hip/hip_runtime.h>
#include <stdint.h>

#define B_  4
#define S_  2048
#define DM_ 1024
#define NH_ 16
#define HD_ 64
#define QSCALE 0.1803368801f   // 0.125 * log2(e): exp2-domain softmax scale

typedef unsigned short ushort_t;
typedef __bf16 bf16x8 __attribute__((ext_vector_type(8)));
typedef float  floatx4 __attribute__((ext_vector_type(4)));
typedef float  floatx16 __attribute__((ext_vector_type(16)));

__device__ __forceinline__ float bf2f(ushort_t u) {
    union { unsigned int i; float f; } v; v.i = ((unsigned int)u) << 16; return v.f;
}
__device__ __forceinline__ ushort_t f2bf(float f) {
    union { float f; unsigned int i; } v; v.f = f;
    unsigned int x = v.i;
    return (ushort_t)((x + 0x7fffu + ((x >> 16) & 1u)) >> 16);
}
__device__ __forceinline__ unsigned int pack_bf16_trunc(float lo, float hi) {
    union { float f; unsigned int u; } a, b;
    a.f = lo; b.f = hi;
    return __builtin_amdgcn_perm(b.u, a.u, 0x07060302u);
}

// ---------------------------------------------------------------------------
// fused f32 -> bf16 conversion: x (8192 blocks) + 4 weights (1024 each)
// ---------------------------------------------------------------------------
__global__ __launch_bounds__(256) void cvt_all_kernel(
    const float* __restrict__ x,  const float* __restrict__ wq,
    const float* __restrict__ wk, const float* __restrict__ wv,
    const float* __restrict__ wo,
    ushort_t* __restrict__ xb,  ushort_t* __restrict__ wqb,
    ushort_t* __restrict__ wkb, ushort_t* __restrict__ wvb,
    ushort_t* __restrict__ wob)
{
    const int blk = blockIdx.x;
    const float* src; ushort_t* dst; int off;
    if (blk < 8192)       { src = x;  dst = xb;  off = blk; }
    else if (blk < 9216)  { src = wq; dst = wqb; off = blk - 8192; }
    else if (blk < 10240) { src = wk; dst = wkb; off = blk - 9216; }
    else if (blk < 11264) { src = wv; dst = wvb; off = blk - 10240; }
    else                  { src = wo; dst = wob; off = blk - 11264; }
    const int i = off * 256 + threadIdx.x;
    float4 v = ((const float4*)src)[i];
    ushort4 o; o.x = f2bf(v.x); o.y = f2bf(v.y); o.z = f2bf(v.z); o.w = f2bf(v.w);
    ((ushort4*)dst)[i] = o;
}

// ---------------------------------------------------------------------------
// GEMM: C = A @ B^T, BK=32, 32x32x16 MFMA, 2x2 wave grid, 2x2 tiles/wave.
// (unchanged from R7 — 87.9 us, 586 TF)
// ---------------------------------------------------------------------------
__global__ __launch_bounds__(256, 4) void gemm_bt_kernel(
    const ushort_t* __restrict__ A,
    const ushort_t* __restrict__ B0, const ushort_t* __restrict__ B1,
    const ushort_t* __restrict__ B2,
    void* __restrict__ C0, void* __restrict__ C1, void* __restrict__ C2,
    const float* __restrict__ cf, const float* __restrict__ sf,
    int M, int N, int K, int mode)
{
    __shared__ ushort_t As[128 * 32];
    __shared__ ushort_t Bs[128 * 32];
    const int z = blockIdx.z;
    const ushort_t* Bw = z == 0 ? B0 : z == 1 ? B1 : B2;
    void* Cv           = z == 0 ? C0 : z == 1 ? C1 : C2;

    const int tid  = threadIdx.x;
    const int mbase = blockIdx.x * 128;
    const int nbase = blockIdx.y * 128;
    const int wave = tid >> 6, lane = tid & 63;
    const int l31 = lane & 31, h = lane >> 5;
    const int wm = (wave & 1) * 64, wn = (wave >> 1) * 64;

    floatx16 acc[2][2] = {};

    const int e0 = tid * 8;
    for (int kt = 0; kt < K; kt += 32) {
        __syncthreads();
#pragma unroll
        for (int r = 0; r < 2; ++r) {
            const int e   = e0 + r * 2048;
            const int row = e >> 5;
            const int cp  = (e >> 3) & 3;
            const int cl  = (cp - (row >> 1)) & 3;   // logical chunk stored here
            const ushort_t* ga = A  + (size_t)(mbase + row) * K + kt + cl * 8;
            const ushort_t* gb = Bw + (size_t)(nbase + row) * K + kt + cl * 8;
            __builtin_amdgcn_global_load_lds(
                (const __attribute__((address_space(1))) unsigned int*)ga,
                (__attribute__((address_space(3))) unsigned int*)(As + e), 16, 0, 0);
            __builtin_amdgcn_global_load_lds(
                (const __attribute__((address_space(1))) unsigned int*)gb,
                (__attribute__((address_space(3))) unsigned int*)(Bs + e), 16, 0, 0);
        }
        __builtin_amdgcn_s_waitcnt(0);
        __syncthreads();

#pragma unroll
        for (int kk = 0; kk < 2; ++kk) {
            const int cswz = (kk * 2 + h + (l31 >> 1)) & 3;   // physical chunk
            bf16x8 af[2], bfr[2];
#pragma unroll
            for (int t = 0; t < 2; ++t) {
                af[t]  = *(const bf16x8*)(As + (wm + t * 32 + l31) * 32 + cswz * 8);
                bfr[t] = *(const bf16x8*)(Bs + (wn + t * 32 + l31) * 32 + cswz * 8);
            }
#pragma unroll
            for (int mt = 0; mt < 2; ++mt)
#pragma unroll
                for (int nt = 0; nt < 2; ++nt)
                    acc[mt][nt] = __builtin_amdgcn_mfma_f32_32x32x16_bf16(
                        af[mt], bfr[nt], acc[mt][nt], 0, 0, 0);
        }
    }

    // ---- epilogues. 32x32 C layout: col=n=l31, row=m=(reg&3)+8*(reg>>2)+4h
    const int p = l31 & 1;
    if (mode == 0 && z < 2) {
        ushort_t* Qo = (ushort_t*)Cv;
        const float qs = (z == 0) ? QSCALE : 1.0f;
#pragma unroll
        for (int mt = 0; mt < 2; ++mt)
#pragma unroll
        for (int nt = 0; nt < 2; ++nt) {
            const int col = nbase + wn + nt * 32 + l31;
            const int hh = col >> 6, j = (col & 63) >> 1, de = col & 62;
            float other[16];
#pragma unroll
            for (int i = 0; i < 16; ++i)
                other[i] = __shfl_xor(acc[mt][nt][i], 1, 64);
#pragma unroll
            for (int u = 0; u < 8; ++u) {
                const int i = p * 8 + u;   // even lanes: regs 0-7; odd: 8-15
                const int m = mbase + wm + mt * 32 + (i & 3) + 8 * (i >> 2) + 4 * h;
                const int bb = m >> 11, ss = m & 2047;   // ss = seq position
                const float my = acc[mt][nt][i], ot = other[i];
                const float e = p ? ot : my;
                const float o = p ? my : ot;
                const float c = cf[ss * 32 + j], sn = sf[ss * 32 + j];
                const float oe = (e * c - o * sn) * qs;
                const float oo = (e * sn + o * c) * qs;
                unsigned pk = (unsigned)f2bf(oe) | ((unsigned)f2bf(oo) << 16);
                *(unsigned*)&Qo[(((size_t)(bb * NH_ + hh)) * S_ + ss) * HD_ + de] = pk;
            }
        }
    } else if (mode == 0) {
        ushort_t* Vo = (ushort_t*)Cv;
#pragma unroll
        for (int mt = 0; mt < 2; ++mt)
#pragma unroll
        for (int nt = 0; nt < 2; ++nt) {
            const int col = nbase + wn + nt * 32 + l31;
            const int hh = col >> 6, d = col & 63;
#pragma unroll
            for (int c = 0; c < 4; ++c) {
                const int s0 = mbase + wm + mt * 32 + 8 * c + 4 * h;
                const int bb = s0 >> 11, ss = s0 & 2047;
                uint2 pk;
                pk.x = (unsigned)f2bf(acc[mt][nt][c * 4 + 0]) |
                       ((unsigned)f2bf(acc[mt][nt][c * 4 + 1]) << 16);
                pk.y = (unsigned)f2bf(acc[mt][nt][c * 4 + 2]) |
                       ((unsigned)f2bf(acc[mt][nt][c * 4 + 3]) << 16);
                *(uint2*)&Vo[((size_t)((bb * NH_ + hh) * HD_ + d)) * S_ + ss] = pk;
            }
        }
    } else {
        float* Co = (float*)Cv;
#pragma unroll
        for (int mt = 0; mt < 2; ++mt)
#pragma unroll
        for (int nt = 0; nt < 2; ++nt) {
            const int col = nbase + wn + nt * 32 + l31;
            float other[16];
#pragma unroll
            for (int i = 0; i < 16; ++i)
                other[i] = __shfl_xor(acc[mt][nt][i], 1, 64);
#pragma unroll
            for (int u = 0; u < 8; ++u) {
                const int i = p * 8 + u;
                const int m = mbase + wm + mt * 32 + (i & 3) + 8 * (i >> 2) + 4 * h;
                float2 v;
                v.x = p ? other[i] : acc[mt][nt][i];
                v.y = p ? acc[mt][nt][i] : other[i];
                *(float2*)&Co[(size_t)m * N + (col & ~1)] = v;
            }
        }
    }
}

// ---------------------------------------------------------------------------
// Causal flash attention, S^T/O^T with 32x32x16 MFMA, exp2-domain softmax.
// Q,K in (B,H,S,64) (Q pre-scaled+roped); V in (B,H,64,S) pre-transposed.
// Block = 4 waves x 32 q-rows; pairs {p,15-p} for uniform 34 tiles.
// P path: key-permutation sigma(32nt+16half+8h+4a+r)=32nt+8(2half+a)+4h+r
// applied to BOTH P^T (B-frag) and V^T (A-frag) — sum over keys invariant.
// C-layout then hands each lane its B-frag as st[nt][8*half+0..7] directly:
// NO LDS round trip, no fence. V A-frags read as two b64 chunks (p0, p0+8).
// ---------------------------------------------------------------------------
__global__ __launch_bounds__(256, 2) void attn_kernel(
    const ushort_t* __restrict__ Qg, const ushort_t* __restrict__ Kg,
    const ushort_t* __restrict__ Vg, ushort_t* __restrict__ Og)
{
    __shared__ ushort_t Ks[64 * 72];       // [key][dim], pad 72
    __shared__ ushort_t Vt[64 * 72];       // [dim][key ^ chunk-swizzle], pad 72

    const int pair = blockIdx.x;           // 0..7
    const int bh   = blockIdx.y;
    const int tid  = threadIdx.x;
    const int wave = tid >> 6, lane = tid & 63;
    const int l31 = lane & 31, h = lane >> 5;

    const size_t bh_off = (size_t)bh * S_ * HD_;
    const int trow = tid >> 3;             // 0..31
    const int tcol = (tid & 7) * 8;        // 0..56
    const int b_out = bh >> 4, h_out = bh & 15;

#pragma unroll 1
    for (int seg = 0; seg < 2; ++seg) {
        const int qtile = seg ? (15 - pair) : pair;
        const int qbase = qtile * 128;
        const int nkt   = 2 * qtile + 2;
        const int qrow  = qbase + wave * 32 + l31;

        bf16x8 qf[4];
#pragma unroll
        for (int ks = 0; ks < 4; ++ks)
            qf[ks] = *(const bf16x8*)(Qg + bh_off + (size_t)qrow * HD_ + ks * 16 + h * 8);

        float m_run = -1e30f, l_run = 0.f;
        floatx16 o_acc[2] = {};

        for (int kt = 0; kt < nkt; ++kt) {
            const int kbase = kt * 64;
            __syncthreads();
            // ---- stage K [key][dim] and V^T [dim][key^swz] — all b128 ----
#pragma unroll
            for (int r = 0; r < 2; ++r) {
                const int row = trow + r * 32;
                *(bf16x8*)(Ks + row * 72 + tcol) =
                    *(const bf16x8*)(Kg + bh_off + (size_t)(kbase + row) * HD_ + tcol);
                const int c = tid + r * 256;
                const int d = c >> 3, k0 = (c & 7) * 8;
                bf16x8 vv = *(const bf16x8*)(Vg + bh_off + (size_t)d * S_ + kbase + k0);
                *(bf16x8*)(Vt + d * 72 + (k0 ^ (((d >> 3) & 7) << 3))) = vv;
            }
            __syncthreads();

            if (kbase > qbase + wave * 32 + 31) continue;   // fully masked

            // ---- S^T = K·Q^T ----
            floatx16 st[2] = {};
#pragma unroll
            for (int nt = 0; nt < 2; ++nt) {
                const ushort_t* kr = Ks + (nt * 32 + l31) * 72 + h * 8;
#pragma unroll
                for (int ks = 0; ks < 4; ++ks) {
                    bf16x8 kf = *(const bf16x8*)(kr + ks * 16);
                    st[nt] = __builtin_amdgcn_mfma_f32_32x32x16_bf16(kf, qf[ks], st[nt], 0, 0, 0);
                }
            }
            // ---- causal mask (diagonal tiles only) ----
            if (kbase + 63 > qbase + wave * 32) {
#pragma unroll
                for (int nt = 0; nt < 2; ++nt) {
                    const int key0 = kbase + nt * 32 + 4 * h;
#pragma unroll
                    for (int c = 0; c < 4; ++c)
#pragma unroll
                        for (int r = 0; r < 4; ++r)
                            if (key0 + 8 * c + r > qrow) st[nt][c * 4 + r] = -1e9f;
                }
            }
            // ---- online softmax, exp2 domain ----
            float mx = st[0][0];
#pragma unroll
            for (int nt = 0; nt < 2; ++nt)
#pragma unroll
                for (int i = 0; i < 16; ++i) mx = fmaxf(mx, st[nt][i]);
            mx = fmaxf(mx, __shfl_xor(mx, 32, 64));
            const float mnew = fmaxf(m_run, mx);
            const float alpha = __builtin_amdgcn_exp2f(m_run - mnew);
            m_run = mnew;
            float sum = 0.f;
#pragma unroll
            for (int nt = 0; nt < 2; ++nt)
#pragma unroll
                for (int i = 0; i < 16; ++i) {
                    const float pv = __builtin_amdgcn_exp2f(st[nt][i] - mnew);
                    st[nt][i] = pv; sum += pv;
                }
            sum += __shfl_xor(sum, 32, 64);
            l_run = l_run * alpha + sum;
#pragma unroll
            for (int dt = 0; dt < 2; ++dt)
#pragma unroll
                for (int i = 0; i < 16; ++i) o_acc[dt][i] *= alpha;

            // ---- P^T B-frags directly from C-layout regs (sigma-permuted) ----
            bf16x8 pf[4];
#pragma unroll
            for (int ks = 0; ks < 4; ++ks) {
                const int nt = ks >> 1, half = ks & 1;
                union { uint4 q; bf16x8 v; } u;
                u.q.x = pack_bf16_trunc(st[nt][8 * half + 0], st[nt][8 * half + 1]);
                u.q.y = pack_bf16_trunc(st[nt][8 * half + 2], st[nt][8 * half + 3]);
                u.q.z = pack_bf16_trunc(st[nt][8 * half + 4], st[nt][8 * half + 5]);
                u.q.w = pack_bf16_trunc(st[nt][8 * half + 6], st[nt][8 * half + 7]);
                pf[ks] = u.v;
            }

            // ---- O^T += V^T·P^T (V A-frags follow the same sigma) ----
#pragma unroll
            for (int dt = 0; dt < 2; ++dt) {
                const int d = dt * 32 + l31;
                const int sw = ((d >> 3) & 7) << 3;
                const ushort_t* vr = Vt + d * 72;
#pragma unroll
                for (int ks = 0; ks < 4; ++ks) {
                    const int nt = ks >> 1, half = ks & 1;
                    const int p0 = nt * 32 + half * 16 + 4 * h;
                    union { uint4 q; bf16x8 v; } u;
                    *(uint2*)&u.q.x = *(const uint2*)(vr + (p0 ^ sw));
                    *(uint2*)&u.q.z = *(const uint2*)(vr + ((p0 + 8) ^ sw));
                    o_acc[dt] = __builtin_amdgcn_mfma_f32_32x32x16_bf16(u.v, pf[ks], o_acc[dt], 0, 0, 0);
                }
            }
        }

        // ---- epilogue: normalize, write bf16 (B,S,H*64) ----
        const float inv = 1.0f / l_run;
        ushort_t* orow = Og + ((size_t)(b_out * S_ + qrow)) * DM_ + h_out * HD_;
#pragma unroll
        for (int dt = 0; dt < 2; ++dt)
#pragma unroll
            for (int c = 0; c < 4; ++c) {
                uint2 pk;
                pk.x = (unsigned)f2bf(o_acc[dt][c * 4 + 0] * inv) |
                       ((unsigned)f2bf(o_acc[dt][c * 4 + 1] * inv) << 16);
                pk.y = (unsigned)f2bf(o_acc[dt][c * 4 + 2] * inv) |
                       ((unsigned)f2bf(o_acc[dt][c * 4 + 3] * inv) << 16);
                *(uint2*)(orow + dt * 32 + 8 * c + 4 * h) = pk;
            }
    }
}

// ---------------------------------------------------------------------------
extern "C" void kernel_launch(void* const* d_in, const int* in_sizes, int n_in,
                              void* d_out, int out_size, void* d_ws, size_t ws_size,
                              hipStream_t stream)
{
    const float* x  = (const float*)d_in[0];
    const float* cf = (const float*)d_in[1];
    const float* sf = (const float*)d_in[2];
    // d_in[3] = causal_mask: computed analytically, never read
    const float* wq = (const float*)d_in[4];
    const float* wk = (const float*)d_in[5];
    const float* wv = (const float*)d_in[6];
    const float* wo = (const float*)d_in[7];
    float* out = (float*)d_out;

    const size_t NELEM = (size_t)B_ * S_ * DM_;   // 8388608
    const size_t WELEM = (size_t)DM_ * DM_;       // 1048576
    ushort_t* xb  = (ushort_t*)d_ws;
    ushort_t* qb  = xb + NELEM;
    ushort_t* kb  = qb + NELEM;
    ushort_t* vb  = kb + NELEM;                   // V^T (B,H,64,S)
    ushort_t* ao  = vb + NELEM;
    ushort_t* wqb = ao + NELEM;
    ushort_t* wkb = wqb + WELEM;
    ushort_t* wvb = wkb + WELEM;
    ushort_t* wob = wvb + WELEM;

    cvt_all_kernel<<<dim3(8192 + 4 * 1024), 256, 0, stream>>>(
        x, wq, wk, wv, wo, xb, wqb, wkb, wvb, wob);

    const int M = B_ * S_;
    // fused QKV GEMM with in-epilogue RoPE (Q,K) and V^T store
    gemm_bt_kernel<<<dim3(M / 128, DM_ / 128, 3), 256, 0, stream>>>(
        xb, wqb, wkb, wvb, qb, kb, vb, cf, sf, M, DM_, DM_, 0);
    attn_kernel<<<dim3(8, B_ * NH_), 256, 0, stream>>>(qb, kb, vb, ao);
    gemm_bt_kernel<<<dim3(M / 128, DM_ / 128, 1), 256, 0, stream>>>(
        ao, wob, wob, wob, out, out, out, cf, sf, M, DM_, DM_, 1);
}